// Round 7
// baseline (2572.491 us; speedup 1.0000x reference)
//
#include <hip/hip_runtime.h>
#include <hip/hip_bf16.h>

#define T_DIM 256
#define B_DIM 256
#define E_DIM 256
#define H_DIM 512
#define V_DIM 50257
#define SENT  0x7F7F7F7Fu   // memset byte 0x7F; bf16 |h|<=1 can never be 0x7F7F

typedef __attribute__((ext_vector_type(8))) short short8;
typedef __attribute__((ext_vector_type(4))) float f32x4;
typedef __attribute__((ext_vector_type(4))) unsigned int uint4v;
typedef __attribute__((ext_vector_type(2))) unsigned int uint2v;

__device__ __forceinline__ unsigned short f2bf(float f) {
    union { float f; unsigned u; } v; v.f = f;
    unsigned r = v.u + 0x7FFFu + ((v.u >> 16) & 1u);
    return (unsigned short)(r >> 16);
}
__device__ __forceinline__ short cvt_bf(float f) { return (short)f2bf(f); }
__device__ __forceinline__ float sigmoidf_(float x) {
    return 1.0f / (1.0f + __expf(-x));
}
__device__ __forceinline__ float tanhf_(float x) {
    float xc = fminf(fmaxf(x, -15.0f), 15.0f);
    float e = __expf(2.0f * xc);
    return (e - 1.0f) / (e + 1.0f);
}

// All h traffic goes through the MALL (sc0 sc1): correct for ANY block->XCD
// placement. Data carries its own "ready" signal (sentinel pattern), so there
// are no flags, no release drains, and no possible deadlock: the store always
// reaches the MALL, the re-load loop always terminates when it does.
// Loads return in-flight; callers must s_waitcnt + sched_barrier(0) (rule #18).
__device__ __forceinline__ short8 load16_mall(const unsigned short* p) {
    short8 r;
    asm volatile("global_load_dwordx4 %0, %1, off sc0 sc1"
                 : "=v"(r) : "v"(p) : "memory");
    return r;
}
__device__ __forceinline__ void store8_mall(unsigned short* p, uint2v v) {
    asm volatile("global_store_dwordx2 %0, %1, off sc0 sc1"
                 :: "v"(p), "v"(v) : "memory");
}
__device__ __forceinline__ bool frag_ready(short8 v) {
    union { short8 s; uint4v u; } c; c.s = v;
    return (c.u[0] != SENT) & (c.u[1] != SENT) & (c.u[2] != SENT) & (c.u[3] != SENT);
}

// ---------------- LSTM persistent kernel ----------------
// 256 blocks, 1/CU (96 KiB LDS). Static roles: bg = blk&7 (32 batch rows),
// hg = blk>>3 (16 hidden cols). Weights slice staged once in LDS as W^T
// fragments; swapped-operand MFMA (gates^T = W^T * in^T) -> each lane owns
// one batch row x 4 consecutive hidden cols -> one 8B packed h store.
// h state: hbuf[t] = h_t, one slot per step (no reuse -> no ABA, no flags).
// Step t: speculatively issue h_t loads, do x-GEMM, then sentinel-check and
// re-load missing fragments, h-GEMM, elementwise update, store h_{t+1}.
__global__ void __launch_bounds__(128, 1)
lstm_persist(const float* __restrict__ x,
             const float* __restrict__ wk,
             const float* __restrict__ bias,
             unsigned short* __restrict__ hbuf)   // [T+1][B][H] bf16, 0x7F-filled
{
    extern __shared__ unsigned short lds_w[];     // [96 frag][64 lane][8]
    const int tid = threadIdx.x;
    const int blk = blockIdx.x;
    const int bg  = blk & 7;
    const int hg  = blk >> 3;
    const int bb  = bg * 32;
    const int hh  = hg * 16;

    // ---- preload weights into LDS as W^T fragments (once) ----
    // frag f=kt*4+g; lane l; elem j -> W[kt*32+(l>>4)*8+j][g*512+hh+(l&15)]
    for (int f = 0; f < 96; ++f) {
        const int kt = f >> 2, g = f & 3;
        for (int idx = tid; idx < 512; idx += 128) {
            const int c  = idx & 15;
            const int hi = (idx >> 4) & 3;
            const int j  = idx >> 6;
            const int k  = kt * 32 + hi * 8 + j;
            const int col = g * 512 + hh + c;
            lds_w[(f * 64 + hi * 16 + c) * 8 + j] = f2bf(wk[(size_t)k * 2048 + col]);
        }
    }
    __syncthreads();

    const int w    = tid >> 6;        // wave: batch rows [bb+w*16, +16)
    const int lane = tid & 63;
    const int lc   = lane & 15;
    const int lk   = lane >> 4;

    // biases for this lane's 4 hidden cols (hh + lk*4 + j), per gate
    const f32x4 bi  = *(const f32x4*)(bias + 0 * 512 + hh + lk * 4);
    const f32x4 bj  = *(const f32x4*)(bias + 1 * 512 + hh + lk * 4);
    f32x4       bf_ = *(const f32x4*)(bias + 2 * 512 + hh + lk * 4);
    const f32x4 bo  = *(const f32x4*)(bias + 3 * 512 + hh + lk * 4);
    bf_ = bf_ + 1.0f;                                  // FORGET_BIAS

    f32x4 c_frag = {0.f, 0.f, 0.f, 0.f};

    const int arow = bb + w * 16 + lc;                 // batch row (loads & store)
    const float* xbase = x + (size_t)arow * E_DIM + lk * 8;
    const size_t hrow_off = (size_t)arow * H_DIM + lk * 8;   // read side
    const size_t hsto_off = (size_t)arow * H_DIM + hh + lk * 4; // write side

    for (int t = 0; t < T_DIM; ++t) {
        // ---- 1. speculative h_t loads, issued before anything else ----
        short8 hfr[16];
        const unsigned short* hr = hbuf + (size_t)t * (B_DIM * H_DIM) + hrow_off;
        if (t > 0) {
            #pragma unroll
            for (int k = 0; k < 16; ++k)
                hfr[k] = load16_mall(hr + k * 32);
        }

        // ---- 2. x part (independent of h_t; hides h-load latency) ----
        f32x4 a0 = {0.f,0.f,0.f,0.f}, a1 = a0, a2 = a0, a3 = a0;
        const float* xr = xbase + (size_t)t * (B_DIM * E_DIM);
        #pragma unroll
        for (int kt = 0; kt < 8; ++kt) {
            const float* p = xr + kt * 32;
            const f32x4 lo = *(const f32x4*)p;
            const f32x4 hi = *(const f32x4*)(p + 4);
            short8 a;
            a[0]=cvt_bf(lo[0]); a[1]=cvt_bf(lo[1]); a[2]=cvt_bf(lo[2]); a[3]=cvt_bf(lo[3]);
            a[4]=cvt_bf(hi[0]); a[5]=cvt_bf(hi[1]); a[6]=cvt_bf(hi[2]); a[7]=cvt_bf(hi[3]);
            const unsigned short* wp = lds_w + ((size_t)(kt * 4) * 64 + lane) * 8;
            a0 = __builtin_amdgcn_mfma_f32_16x16x32_bf16(*(const short8*)(wp +    0), a, a0, 0,0,0);
            a1 = __builtin_amdgcn_mfma_f32_16x16x32_bf16(*(const short8*)(wp +  512), a, a1, 0,0,0);
            a2 = __builtin_amdgcn_mfma_f32_16x16x32_bf16(*(const short8*)(wp + 1024), a, a2, 0,0,0);
            a3 = __builtin_amdgcn_mfma_f32_16x16x32_bf16(*(const short8*)(wp + 1536), a, a3, 0,0,0);
        }

        if (t > 0) {
            // ---- 3. sentinel check; re-load only missing fragments ----
            asm volatile("s_waitcnt vmcnt(0)" ::: "memory");
            __builtin_amdgcn_sched_barrier(0);
            unsigned pend = 0;
            #pragma unroll
            for (int k = 0; k < 16; ++k)
                pend |= frag_ready(hfr[k]) ? 0u : (1u << k);
            #pragma unroll 1
            while (!__all(pend == 0)) {
                #pragma unroll
                for (int k = 0; k < 16; ++k)
                    if (pend & (1u << k)) hfr[k] = load16_mall(hr + k * 32);
                asm volatile("s_waitcnt vmcnt(0)" ::: "memory");
                __builtin_amdgcn_sched_barrier(0);
                unsigned np = 0;
                #pragma unroll
                for (int k = 0; k < 16; ++k)
                    if (pend & (1u << k))
                        np |= frag_ready(hfr[k]) ? 0u : (1u << k);
                pend = np;
            }
            __builtin_amdgcn_sched_barrier(0);

            // ---- 4. h part ----
            #pragma unroll
            for (int k = 0; k < 16; ++k) {
                const unsigned short* wp = lds_w + ((size_t)((8 + k) * 4) * 64 + lane) * 8;
                a0 = __builtin_amdgcn_mfma_f32_16x16x32_bf16(*(const short8*)(wp +    0), hfr[k], a0, 0,0,0);
                a1 = __builtin_amdgcn_mfma_f32_16x16x32_bf16(*(const short8*)(wp +  512), hfr[k], a1, 0,0,0);
                a2 = __builtin_amdgcn_mfma_f32_16x16x32_bf16(*(const short8*)(wp + 1024), hfr[k], a2, 0,0,0);
                a3 = __builtin_amdgcn_mfma_f32_16x16x32_bf16(*(const short8*)(wp + 1536), hfr[k], a3, 0,0,0);
            }
        }

        // ---- 5. lane-local LSTM update; fire-and-forget 8B store of h_{t+1} ----
        unsigned short hu[4];
        #pragma unroll
        for (int j = 0; j < 4; ++j) {
            const float iv = a0[j] + bi[j];
            const float jv = a1[j] + bj[j];
            const float fv = a2[j] + bf_[j];
            const float ov = a3[j] + bo[j];
            const float cn = sigmoidf_(fv) * c_frag[j] + sigmoidf_(iv) * tanhf_(jv);
            c_frag[j] = cn;
            hu[j] = f2bf(sigmoidf_(ov) * tanhf_(cn));
        }
        uint2v pk;
        pk[0] = (unsigned)hu[0] | ((unsigned)hu[1] << 16);
        pk[1] = (unsigned)hu[2] | ((unsigned)hu[3] << 16);
        store8_mall(hbuf + (size_t)(t + 1) * (B_DIM * H_DIM) + hsto_off, pk);
        // no drain, no flag: the data itself signals readiness at the MALL
    }
}

// ---------------- final projection: out = h_last @ W_out + b_out ----------------
__global__ void __launch_bounds__(256)
proj_gemm(const unsigned short* __restrict__ h,   // [256][512] bf16 (slot T)
          const float* __restrict__ wout,         // [512][V]
          const float* __restrict__ bout,         // [V]
          float* __restrict__ out)                // [256][V]
{
    const int tid  = threadIdx.x;
    const int w    = tid >> 6;
    const int lane = tid & 63;
    const int lc   = lane & 15;
    const int lk   = lane >> 4;
    const int n0   = blockIdx.x * 128 + w * 32;

    f32x4 acc[16][2];
    #pragma unroll
    for (int mt = 0; mt < 16; ++mt) {
        acc[mt][0] = (f32x4){0.f,0.f,0.f,0.f};
        acc[mt][1] = (f32x4){0.f,0.f,0.f,0.f};
    }
    int ncl[2];
    ncl[0] = min(n0 + lc,      V_DIM - 1);
    ncl[1] = min(n0 + 16 + lc, V_DIM - 1);

    #pragma unroll 4
    for (int kt = 0; kt < 16; ++kt) {
        short8 bfr[2];
        #pragma unroll
        for (int nt = 0; nt < 2; ++nt) {
            #pragma unroll
            for (int j = 0; j < 8; ++j) {
                const int k = kt * 32 + lk * 8 + j;
                bfr[nt][j] = (short)f2bf(wout[(size_t)k * V_DIM + ncl[nt]]);
            }
        }
        #pragma unroll
        for (int mt = 0; mt < 16; ++mt) {
            const short8 a = *(const short8*)(h + (size_t)(mt * 16 + lc) * H_DIM
                                                + kt * 32 + lk * 8);
            acc[mt][0] = __builtin_amdgcn_mfma_f32_16x16x32_bf16(a, bfr[0], acc[mt][0], 0,0,0);
            acc[mt][1] = __builtin_amdgcn_mfma_f32_16x16x32_bf16(a, bfr[1], acc[mt][1], 0,0,0);
        }
    }

    #pragma unroll
    for (int nt = 0; nt < 2; ++nt) {
        const int n = n0 + nt * 16 + lc;
        if (n < V_DIM) {
            const float bb = bout[n];
            #pragma unroll
            for (int mt = 0; mt < 16; ++mt)
                #pragma unroll
                for (int j = 0; j < 4; ++j)
                    out[(size_t)(mt * 16 + lk * 4 + j) * V_DIM + n] = acc[mt][nt][j] + bb;
        }
    }
}

extern "C" void kernel_launch(void* const* d_in, const int* in_sizes, int n_in,
                              void* d_out, int out_size, void* d_ws, size_t ws_size,
                              hipStream_t stream) {
    const float* x    = (const float*)d_in[0];
    const float* wk   = (const float*)d_in[1];
    const float* bias = (const float*)d_in[2];
    const float* wout = (const float*)d_in[3];
    const float* bout = (const float*)d_in[4];
    float* out = (float*)d_out;

    // hbuf: (T+1) slots of [B][H] bf16 = 257 * 256KiB ~= 64.3 MB
    unsigned short* hbuf = (unsigned short*)d_ws;
    const size_t hbuf_bytes = (size_t)(T_DIM + 1) * B_DIM * H_DIM * 2;

    // Re-sentinel every call (graph-replay safe; slots are written once per
    // run so no reuse hazards). Byte 0x7F -> dword 0x7F7F7F7F, unreachable
    // by any produced bf16 h value (|h| <= 1).
    hipMemsetAsync(hbuf, 0x7F, hbuf_bytes, stream);

    hipFuncSetAttribute((const void*)lstm_persist,
                        hipFuncAttributeMaxDynamicSharedMemorySize, 96 * 1024);

    hipLaunchKernelGGL(lstm_persist, dim3(256), dim3(128), 96 * 1024, stream,
                       x, wk, bias, hbuf);
    // h_last = slot T; lstm kernel-end release + proj dispatch acquire make
    // it visible device-wide.
    hipLaunchKernelGGL(proj_gemm, dim3((V_DIM + 127) / 128), dim3(256), 0, stream,
                       hbuf + (size_t)T_DIM * B_DIM * H_DIM, wout, bout, out);
}

// Round 8
// 1556.636 us; speedup vs baseline: 1.6526x; 1.6526x over previous
//
#include <hip/hip_runtime.h>
#include <hip/hip_bf16.h>

#define T_DIM 256
#define B_DIM 256
#define E_DIM 256
#define H_DIM 512
#define V_DIM 50257
#define BH    (B_DIM * H_DIM)          // elems per h slot
#define PRE_AHEAD 5                    // at step t, re-arm slot t+5
#define SENT  0x7F7F7F7Fu              // bf16 |h|<=1 can never be 0x7F7F

typedef __attribute__((ext_vector_type(8))) short short8;
typedef __attribute__((ext_vector_type(4))) float f32x4;
typedef __attribute__((ext_vector_type(4))) unsigned int uint4v;
typedef __attribute__((ext_vector_type(2))) unsigned int uint2v;

__device__ __forceinline__ unsigned short f2bf(float f) {
    union { float f; unsigned u; } v; v.f = f;
    unsigned r = v.u + 0x7FFFu + ((v.u >> 16) & 1u);
    return (unsigned short)(r >> 16);
}
__device__ __forceinline__ short cvt_bf(float f) { return (short)f2bf(f); }
__device__ __forceinline__ float sigmoidf_(float x) {
    return 1.0f / (1.0f + __expf(-x));
}
__device__ __forceinline__ float tanhf_(float x) {
    float xc = fminf(fmaxf(x, -15.0f), 15.0f);
    float e = __expf(2.0f * xc);
    return (e - 1.0f) / (e + 1.0f);
}

// All h traffic via MALL (sc0 sc1): placement-independent. Data carries its
// own readiness (sentinel); producers are WAIT-FREE (fire stores, move on),
// so no circular wait exists anywhere -> deadlock impossible by construction.
// Loads return in-flight; callers must s_waitcnt + sched_barrier(0) (rule #18).
__device__ __forceinline__ short8 load16_mall(const unsigned short* p) {
    short8 r;
    asm volatile("global_load_dwordx4 %0, %1, off sc0 sc1"
                 : "=v"(r) : "v"(p) : "memory");
    return r;
}
__device__ __forceinline__ void store8_mall(unsigned short* p, uint2v v) {
    asm volatile("global_store_dwordx2 %0, %1, off sc0 sc1"
                 :: "v"(p), "v"(v) : "memory");
}
__device__ __forceinline__ bool frag_ready(short8 v) {
    union { short8 s; uint4v u; } c; c.s = v;
    return (c.u[0] != SENT) & (c.u[1] != SENT) & (c.u[2] != SENT) & (c.u[3] != SENT);
}

// ---------------- LSTM persistent kernel ----------------
// 256 blocks, 1/CU (96 KiB LDS). bg = blk&7 (32 batch rows), hg = blk>>3
// (16 hidden cols). Weights staged once in LDS as W^T fragments; swapped
// MFMA (gates^T = W^T * in^T) -> lane owns 1 batch row x 4 consecutive cols.
// h state: hbuf[t] = h_t, one slot/step (write-once). Sentinel protocol:
//  - memset arms slots 0..4 once per call (1.3 MB);
//  - at step t each producer re-arms ITS output region of slot t+5 (8B/lane,
//    fire-and-forget). Consumer at step u implies producers >= step u-1, so
//    slot u is armed >= 4 steps before any sweep (also kills replay staleness).
//  - step t: xMFMA (regs prefetched) -> issue x(t+1) prefetch -> sweep slot t
//    -> sparse resweep until sentinel-free -> hMFMA -> update -> fire h(t+1)
//    data store + slot t+5 arm. No flags, no drains, producers never wait.
__global__ void __launch_bounds__(128, 1)
lstm_persist(const float* __restrict__ x,
             const float* __restrict__ wk,
             const float* __restrict__ bias,
             unsigned short* __restrict__ hbuf)   // [T+1][B][H] bf16
{
    extern __shared__ unsigned short lds_w[];     // [96 frag][64 lane][8]
    const int tid = threadIdx.x;
    const int blk = blockIdx.x;
    const int bg  = blk & 7;
    const int hg  = blk >> 3;
    const int bb  = bg * 32;
    const int hh  = hg * 16;

    // ---- preload weights into LDS as W^T fragments (once) ----
    // frag f=kt*4+g; lane l; elem j -> W[kt*32+(l>>4)*8+j][g*512+hh+(l&15)]
    for (int f = 0; f < 96; ++f) {
        const int kt = f >> 2, g = f & 3;
        for (int idx = tid; idx < 512; idx += 128) {
            const int c  = idx & 15;
            const int hi = (idx >> 4) & 3;
            const int j  = idx >> 6;
            const int k  = kt * 32 + hi * 8 + j;
            const int col = g * 512 + hh + c;
            lds_w[(f * 64 + hi * 16 + c) * 8 + j] = f2bf(wk[(size_t)k * 2048 + col]);
        }
    }
    __syncthreads();

    const int w    = tid >> 6;        // wave: batch rows [bb+w*16, +16)
    const int lane = tid & 63;
    const int lc   = lane & 15;
    const int lk   = lane >> 4;

    const f32x4 bi  = *(const f32x4*)(bias + 0 * 512 + hh + lk * 4);
    const f32x4 bj  = *(const f32x4*)(bias + 1 * 512 + hh + lk * 4);
    f32x4       bf_ = *(const f32x4*)(bias + 2 * 512 + hh + lk * 4);
    const f32x4 bo  = *(const f32x4*)(bias + 3 * 512 + hh + lk * 4);
    bf_ = bf_ + 1.0f;                                  // FORGET_BIAS

    f32x4 c_frag = {0.f, 0.f, 0.f, 0.f};

    const int arow = bb + w * 16 + lc;                 // batch row
    const float* xbase = x + (size_t)arow * E_DIM + lk * 8;
    const size_t hrow_off = (size_t)arow * H_DIM + lk * 8;      // read side
    const size_t hsto_off = (size_t)arow * H_DIM + hh + lk * 4; // write side

    // ---- x prefetch buffer: 16 x f32x4 (one step's A-operand slice) ----
    f32x4 xreg[16];
    #pragma unroll
    for (int kt = 0; kt < 8; ++kt) {
        const float* p = xbase + kt * 32;
        xreg[2 * kt]     = *(const f32x4*)p;
        xreg[2 * kt + 1] = *(const f32x4*)(p + 4);
    }

    const uint2v sentv = {SENT, SENT};

    for (int t = 0; t < T_DIM; ++t) {
        // ---- 1. x part from prefetched regs (compiler inserts the wait) ----
        f32x4 a0 = {0.f,0.f,0.f,0.f}, a1 = a0, a2 = a0, a3 = a0;
        short8 apk[8];
        #pragma unroll
        for (int kt = 0; kt < 8; ++kt) {
            const f32x4 lo = xreg[2 * kt];
            const f32x4 hi = xreg[2 * kt + 1];
            short8 a;
            a[0]=cvt_bf(lo[0]); a[1]=cvt_bf(lo[1]); a[2]=cvt_bf(lo[2]); a[3]=cvt_bf(lo[3]);
            a[4]=cvt_bf(hi[0]); a[5]=cvt_bf(hi[1]); a[6]=cvt_bf(hi[2]); a[7]=cvt_bf(hi[3]);
            apk[kt] = a;
        }
        #pragma unroll
        for (int kt = 0; kt < 8; ++kt) {
            const unsigned short* wp = lds_w + ((size_t)(kt * 4) * 64 + lane) * 8;
            a0 = __builtin_amdgcn_mfma_f32_16x16x32_bf16(*(const short8*)(wp +    0), apk[kt], a0, 0,0,0);
            a1 = __builtin_amdgcn_mfma_f32_16x16x32_bf16(*(const short8*)(wp +  512), apk[kt], a1, 0,0,0);
            a2 = __builtin_amdgcn_mfma_f32_16x16x32_bf16(*(const short8*)(wp + 1024), apk[kt], a2, 0,0,0);
            a3 = __builtin_amdgcn_mfma_f32_16x16x32_bf16(*(const short8*)(wp + 1536), apk[kt], a3, 0,0,0);
        }

        // ---- 2. issue next step's x prefetch (lands during sweep/hMFMA) ----
        if (t + 1 < T_DIM) {
            const float* xn = xbase + (size_t)(t + 1) * (B_DIM * E_DIM);
            #pragma unroll
            for (int kt = 0; kt < 8; ++kt) {
                const float* p = xn + kt * 32;
                xreg[2 * kt]     = *(const f32x4*)p;
                xreg[2 * kt + 1] = *(const f32x4*)(p + 4);
            }
        }

        if (t > 0) {
            // ---- 3. sweep h_t; sparse resweep until sentinel-free ----
            const unsigned short* hr = hbuf + (size_t)t * BH + hrow_off;
            short8 hfr[16];
            #pragma unroll
            for (int k = 0; k < 16; ++k)
                hfr[k] = load16_mall(hr + k * 32);
            asm volatile("s_waitcnt vmcnt(0)" ::: "memory");
            __builtin_amdgcn_sched_barrier(0);

            unsigned pend = 0;
            #pragma unroll
            for (int k = 0; k < 16; ++k)
                pend |= frag_ready(hfr[k]) ? 0u : (1u << k);
            #pragma unroll 1
            while (!__all(pend == 0)) {
                #pragma unroll
                for (int k = 0; k < 16; ++k)
                    if (pend & (1u << k)) hfr[k] = load16_mall(hr + k * 32);
                asm volatile("s_waitcnt vmcnt(0)" ::: "memory");
                __builtin_amdgcn_sched_barrier(0);
                unsigned np = 0;
                #pragma unroll
                for (int k = 0; k < 16; ++k)
                    if (pend & (1u << k))
                        np |= frag_ready(hfr[k]) ? 0u : (1u << k);
                pend = np;
            }
            __builtin_amdgcn_sched_barrier(0);

            // ---- 4. h part ----
            #pragma unroll
            for (int k = 0; k < 16; ++k) {
                const unsigned short* wp = lds_w + ((size_t)((8 + k) * 4) * 64 + lane) * 8;
                a0 = __builtin_amdgcn_mfma_f32_16x16x32_bf16(*(const short8*)(wp +    0), hfr[k], a0, 0,0,0);
                a1 = __builtin_amdgcn_mfma_f32_16x16x32_bf16(*(const short8*)(wp +  512), hfr[k], a1, 0,0,0);
                a2 = __builtin_amdgcn_mfma_f32_16x16x32_bf16(*(const short8*)(wp + 1024), hfr[k], a2, 0,0,0);
                a3 = __builtin_amdgcn_mfma_f32_16x16x32_bf16(*(const short8*)(wp + 1536), hfr[k], a3, 0,0,0);
            }
        }

        // ---- 5. update + fire-and-forget: h_{t+1} data, slot t+5 re-arm ----
        unsigned short hu[4];
        #pragma unroll
        for (int j = 0; j < 4; ++j) {
            const float iv = a0[j] + bi[j];
            const float jv = a1[j] + bj[j];
            const float fv = a2[j] + bf_[j];
            const float ov = a3[j] + bo[j];
            const float cn = sigmoidf_(fv) * c_frag[j] + sigmoidf_(iv) * tanhf_(jv);
            c_frag[j] = cn;
            hu[j] = f2bf(sigmoidf_(ov) * tanhf_(cn));
        }
        uint2v pk;
        pk[0] = (unsigned)hu[0] | ((unsigned)hu[1] << 16);
        pk[1] = (unsigned)hu[2] | ((unsigned)hu[3] << 16);
        store8_mall(hbuf + (size_t)(t + 1) * BH + hsto_off, pk);
        if (t + PRE_AHEAD <= T_DIM)   // re-arm own region of slot t+5
            store8_mall(hbuf + (size_t)(t + PRE_AHEAD) * BH + hsto_off, sentv);
        // no drain, no flag: data itself signals readiness; ordering of the
        // re-arm (step t) vs the data write (step t+4) is enforced by the
        // vmcnt(0) sweeps of steps t+1..t+4 in between.
    }
}

// ---------------- final projection: out = h_last @ W_out + b_out ----------------
__global__ void __launch_bounds__(256)
proj_gemm(const unsigned short* __restrict__ h,   // [256][512] bf16 (slot T)
          const float* __restrict__ wout,         // [512][V]
          const float* __restrict__ bout,         // [V]
          float* __restrict__ out)                // [256][V]
{
    const int tid  = threadIdx.x;
    const int w    = tid >> 6;
    const int lane = tid & 63;
    const int lc   = lane & 15;
    const int lk   = lane >> 4;
    const int n0   = blockIdx.x * 128 + w * 32;

    f32x4 acc[16][2];
    #pragma unroll
    for (int mt = 0; mt < 16; ++mt) {
        acc[mt][0] = (f32x4){0.f,0.f,0.f,0.f};
        acc[mt][1] = (f32x4){0.f,0.f,0.f,0.f};
    }
    int ncl[2];
    ncl[0] = min(n0 + lc,      V_DIM - 1);
    ncl[1] = min(n0 + 16 + lc, V_DIM - 1);

    #pragma unroll 4
    for (int kt = 0; kt < 16; ++kt) {
        short8 bfr[2];
        #pragma unroll
        for (int nt = 0; nt < 2; ++nt) {
            #pragma unroll
            for (int j = 0; j < 8; ++j) {
                const int k = kt * 32 + lk * 8 + j;
                bfr[nt][j] = (short)f2bf(wout[(size_t)k * V_DIM + ncl[nt]]);
            }
        }
        #pragma unroll
        for (int mt = 0; mt < 16; ++mt) {
            const short8 a = *(const short8*)(h + (size_t)(mt * 16 + lc) * H_DIM
                                                + kt * 32 + lk * 8);
            acc[mt][0] = __builtin_amdgcn_mfma_f32_16x16x32_bf16(a, bfr[0], acc[mt][0], 0,0,0);
            acc[mt][1] = __builtin_amdgcn_mfma_f32_16x16x32_bf16(a, bfr[1], acc[mt][1], 0,0,0);
        }
    }

    #pragma unroll
    for (int nt = 0; nt < 2; ++nt) {
        const int n = n0 + nt * 16 + lc;
        if (n < V_DIM) {
            const float bb = bout[n];
            #pragma unroll
            for (int mt = 0; mt < 16; ++mt)
                #pragma unroll
                for (int j = 0; j < 4; ++j)
                    out[(size_t)(mt * 16 + lk * 4 + j) * V_DIM + n] = acc[mt][nt][j] + bb;
        }
    }
}

extern "C" void kernel_launch(void* const* d_in, const int* in_sizes, int n_in,
                              void* d_out, int out_size, void* d_ws, size_t ws_size,
                              hipStream_t stream) {
    const float* x    = (const float*)d_in[0];
    const float* wk   = (const float*)d_in[1];
    const float* bias = (const float*)d_in[2];
    const float* wout = (const float*)d_in[3];
    const float* bout = (const float*)d_in[4];
    float* out = (float*)d_out;

    // hbuf: (T+1) slots of [B][H] bf16 ~= 64.3 MB (proven to fit in R7)
    unsigned short* hbuf = (unsigned short*)d_ws;

    // Arm only slots 0..4 (1.3 MB). Slots >=5 are re-armed just-in-time by
    // producers (step t arms slot t+5), which also wipes stale data from the
    // previous graph replay long before any consumer can sweep it.
    hipMemsetAsync(hbuf, 0x7F, (size_t)PRE_AHEAD * BH * 2, stream);

    hipFuncSetAttribute((const void*)lstm_persist,
                        hipFuncAttributeMaxDynamicSharedMemorySize, 96 * 1024);

    hipLaunchKernelGGL(lstm_persist, dim3(256), dim3(128), 96 * 1024, stream,
                       x, wk, bias, hbuf);
    // h_last = slot T; kernel-end release + dispatch acquire hand it to proj.
    hipLaunchKernelGGL(proj_gemm, dim3((V_DIM + 127) / 128), dim3(256), 0, stream,
                       hbuf + (size_t)T_DIM * BH, wout, bout, out);
}